// Round 3
// baseline (1175.510 us; speedup 1.0000x reference)
//
#include <hip/hip_runtime.h>

#define EPS 1e-5f
#define SELU_L 1.0507009873554805f
#define SELU_A 1.6732632423543772f
#define SELU_LA (SELU_L * SELU_A)

typedef _Float16 half8 __attribute__((ext_vector_type(8)));
typedef _Float16 half4 __attribute__((ext_vector_type(4)));
typedef float floatx4 __attribute__((ext_vector_type(4)));

__device__ __forceinline__ float selu_f(float x) {
    return x > 0.f ? SELU_L * x : SELU_LA * (__expf(x) - 1.f);
}

// async global->LDS, 16B per lane; LDS dest is wave-uniform base + lane*16
__device__ __forceinline__ void gload_lds16(const _Float16* g, _Float16* l) {
    __builtin_amdgcn_global_load_lds(
        (const __attribute__((address_space(1))) void*)g,
        (__attribute__((address_space(3))) void*)l, 16, 0, 0);
}

// ------------- weight swizzle prep: A-operand fragment order, fp16 -------------
// wb_h : [t=18][mi=4][L=64][j=8]  co = mi*16 + (L&15), ci = (t&1)*32 + (L>>4)*8 + j, s = t>>1
// wb_in: [mi=4][L=64][j=8]        k = (L>>4)*8+j -> s=k/3, ci=k%3 (k>=27 -> 0)
// wb_out:[t=18][L=64][j=8]        co = L&15 (valid <3), ci/s as wb_h
// zp   : 32 halves of zeros (OOB redirect target for global_load_lds staging)
__global__ __launch_bounds__(256) void k_prep(
    const float* __restrict__ w_h, const float* __restrict__ w_in,
    const float* __restrict__ w_out, _Float16* __restrict__ wb_h,
    _Float16* __restrict__ wb_in, _Float16* __restrict__ wb_out,
    _Float16* __restrict__ zp)
{
    int i = blockIdx.x * 256 + threadIdx.x;
    if (i < 32) zp[i] = (_Float16)0.f;  // zero page (ws is poisoned between runs)
    if (i < 36864) {
        int t = i >> 11;
        int rem = i & 2047;
        int mi = rem >> 9;
        int L = (rem >> 3) & 63;
        int j = i & 7;
        int co = mi * 16 + (L & 15);
        int ci = ((t & 1) << 5) + ((L >> 4) << 3) + j;
        int s = t >> 1;
        wb_h[i] = (_Float16)w_h[(co * 64 + ci) * 9 + s];
    } else if (i < 36864 + 2048) {
        int e = i - 36864;
        int mi = e >> 9;
        int L = (e >> 3) & 63;
        int j = e & 7;
        int co = mi * 16 + (L & 15);
        int k = ((L >> 4) << 3) + j;
        _Float16 val = (_Float16)0.f;
        if (k < 27) {
            int s = k / 3, ci = k - s * 3;
            val = (_Float16)w_in[(co * 3 + ci) * 9 + s];
        }
        wb_in[e] = val;
    } else if (i < 36864 + 2048 + 9216) {
        int e = i - 36864 - 2048;
        int t = e >> 9;
        int L = (e >> 3) & 63;
        int j = e & 7;
        int co = L & 15;
        int ci = ((t & 1) << 5) + ((L >> 4) << 3) + j;
        int s = t >> 1;
        _Float16 val = (_Float16)0.f;
        if (co < 3) val = (_Float16)w_out[(co * 64 + ci) * 9 + s];
        wb_out[e] = val;
    }
}

// ------------- conv_in: 3 -> 64, BN, SELU, NHWC fp16 out (MFMA, K=32) -------------
__global__ __launch_bounds__(256) void k_conv_in_mfma(
    const float* __restrict__ X, const _Float16* __restrict__ wb,
    const float* __restrict__ bconv, const float* __restrict__ g,
    const float* __restrict__ be, const float* __restrict__ bm,
    const float* __restrict__ bv, _Float16* __restrict__ dst)
{
    __shared__ float s_x[3][18][18];
    __shared__ float s_sc[64], s_bs[64];
    const int tid = threadIdx.x;
    const int w0 = blockIdx.x * 16, h0 = blockIdx.y * 16, b = blockIdx.z;

    if (tid < 64) {
        float sc = g[tid] * rsqrtf(bv[tid] + EPS);
        s_sc[tid] = sc;
        s_bs[tid] = (bconv[tid] - bm[tid]) * sc + be[tid];
    }
    for (int idx = tid; idx < 3 * 324; idx += 256) {
        int ci = idx / 324, rem = idx - ci * 324;
        int r = rem / 18, c = rem - r * 18;
        int gh = h0 - 1 + r, gw = w0 - 1 + c;
        float val = 0.f;
        if ((unsigned)gh < 256u && (unsigned)gw < 256u)
            val = X[((b * 3 + ci) << 16) + (gh << 8) + gw];
        s_x[ci][r][c] = val;
    }
    __syncthreads();

    const int wv = tid >> 6, L = tid & 63, quad = L >> 4, l15 = L & 15;
    half8 a[4];
    #pragma unroll
    for (int mi = 0; mi < 4; ++mi)
        a[mi] = *(const half8*)(wb + (mi * 64 + L) * 8);

    floatx4 acc[4][4];
    #pragma unroll
    for (int mi = 0; mi < 4; ++mi)
        #pragma unroll
        for (int ni = 0; ni < 4; ++ni) acc[mi][ni] = (floatx4){0.f, 0.f, 0.f, 0.f};

    #pragma unroll
    for (int ni = 0; ni < 4; ++ni) {
        half8 bfr;
        #pragma unroll
        for (int j = 0; j < 8; ++j) {
            int k = quad * 8 + j;
            float xv = 0.f;
            if (k < 27) {
                int s = k / 3, ci = k - s * 3;
                int kh = s / 3, kw = s - kh * 3;
                xv = s_x[ci][wv * 4 + ni + kh][l15 + kw];
            }
            bfr[j] = (_Float16)xv;
        }
        #pragma unroll
        for (int mi = 0; mi < 4; ++mi)
            acc[mi][ni] = __builtin_amdgcn_mfma_f32_16x16x32_f16(a[mi], bfr, acc[mi][ni], 0, 0, 0);
    }

    _Float16* db = dst + ((size_t)b << 22);  // b*256*256*64
    #pragma unroll
    for (int mi = 0; mi < 4; ++mi) {
        const int cob = mi * 16 + quad * 4;
        floatx4 sc = *(const floatx4*)(&s_sc[cob]);
        floatx4 bs = *(const floatx4*)(&s_bs[cob]);
        #pragma unroll
        for (int ni = 0; ni < 4; ++ni) {
            half4 ov;
            #pragma unroll
            for (int r = 0; r < 4; ++r)
                ov[r] = (_Float16)selu_f(acc[mi][ni][r] * sc[r] + bs[r]);
            const int row = h0 + wv * 4 + ni, col = w0 + l15;
            *(half4*)(db + ((((row << 8) + col) << 6) + cob)) = ov;
        }
    }
}

// ------------- hidden v4: v3 + amdgpu_waves_per_eu(2,2) to pin the 256-VGPR budget ----
// (round 2 post-mortem: launch_bounds(256,2) only sets a MIN; LLVM targeted 128 VGPRs
//  and spilled the 144-reg weight array -> 106 MB/dispatch scratch writes. Pinning
//  min=max=2 waves/EU makes the allocator budget 256 regs; need ~238 -> no spill.)
// Each wave: 8 rows x 32 output channels; each B-fragment read feeds 2 MFMAs.
// LDS: single 18x18x64 fp16 tile, LINEAR layout (global_load_lds writes base+lane*16).
// 16B chunk (p, slot) holds global channels (slot ^ (p&7))*8 .. +8 (source pre-swizzle);
// reads use byte = p*128 + (((p&7)^slot)<<4) -> conflict-free (verified 0 in v2/v3).
__global__ __launch_bounds__(256)
__attribute__((amdgpu_waves_per_eu(2, 2)))
void k_hidden_v4(
    const _Float16* __restrict__ src, const _Float16* __restrict__ wb,
    const float* __restrict__ bconv, const float* __restrict__ g,
    const float* __restrict__ be, const float* __restrict__ bm,
    const float* __restrict__ bv, const _Float16* __restrict__ zp,
    _Float16* __restrict__ dst)
{
    __shared__ _Float16 s_in[324 * 64];   // 41472 B -> 2 blocks/CU
    __shared__ float s_sc[64], s_bs[64];
    const int tid = threadIdx.x;
    const int wv = tid >> 6, L = tid & 63, quad = L >> 4, l15 = L & 15;
    const int rh = wv >> 1, mh = wv & 1;   // row-half, channel-half
    const int w0 = blockIdx.x * 16, h0 = blockIdx.y * 16, b = blockIdx.z;
    const _Float16* sb = src + ((size_t)b << 22);

    if (tid < 64) {
        float sc = g[tid] * rsqrtf(bv[tid] + EPS);
        s_sc[tid] = sc;
        s_bs[tid] = (bconv[tid] - bm[tid]) * sc + be[tid];
    }

    // ---- this wave's half of the weights -> 144 VGPRs (issued first, L2-resident) ----
    half8 a[18][2];
    #pragma unroll
    for (int t = 0; t < 18; ++t)
        #pragma unroll
        for (int m = 0; m < 2; ++m)
            a[t][m] = *(const half8*)(wb + ((t * 4 + mh * 2 + m) * 64 + L) * 8);

    // ---- stage 18x18x64 halo tile via global_load_lds (wave wv owns pixels [81*wv, +81)) ----
    {
        const int pw = wv * 81;
        #pragma unroll
        for (int rr = 0; rr < 10; ++rr) {
            const int p = pw + rr * 8 + (L >> 3);      // pixel this lane fetches
            const int sd = (L & 7) ^ (p & 7);          // source chunk (pre-swizzle)
            const int rp = p / 18, cl = p - rp * 18;
            const int gh = h0 - 1 + rp, gw = w0 - 1 + cl;
            const _Float16* gp = ((unsigned)gh < 256u && (unsigned)gw < 256u)
                ? sb + ((((gh << 8) + gw) << 6) + (sd << 3)) : zp;
            gload_lds16(gp, &s_in[(pw + rr * 8) << 6]);
        }
        if (L < 8) {  // remainder: 1 pixel (8 chunks) per wave
            const int p = pw + 80;
            const int sd = L ^ (p & 7);
            const int rp = p / 18, cl = p - rp * 18;
            const int gh = h0 - 1 + rp, gw = w0 - 1 + cl;
            const _Float16* gp = ((unsigned)gh < 256u && (unsigned)gw < 256u)
                ? sb + ((((gh << 8) + gw) << 6) + (sd << 3)) : zp;
            gload_lds16(gp, &s_in[(pw + 80) << 6]);
        }
    }
    __syncthreads();   // drains vmcnt: weights + tile staging complete

    floatx4 acc[2][8];
    #pragma unroll
    for (int m = 0; m < 2; ++m)
        #pragma unroll
        for (int ni = 0; ni < 8; ++ni) acc[m][ni] = (floatx4){0.f, 0.f, 0.f, 0.f};

    #pragma unroll
    for (int t = 0; t < 18; ++t) {
        const int s = t >> 1;
        const int kh = s / 3, kw = s - kh * 3;
        const int sb8 = ((t & 1) << 2) + quad;   // chunk slot within pixel
        #pragma unroll
        for (int ni = 0; ni < 8; ++ni) {
            const int p = (rh * 8 + ni + kh) * 18 + l15 + kw;
            half8 bfr = *(const half8*)(&s_in[(p << 6) + (((p & 7) ^ sb8) << 3)]);
            acc[0][ni] = __builtin_amdgcn_mfma_f32_16x16x32_f16(a[t][0], bfr, acc[0][ni], 0, 0, 0);
            acc[1][ni] = __builtin_amdgcn_mfma_f32_16x16x32_f16(a[t][1], bfr, acc[1][ni], 0, 0, 0);
        }
    }

    // epilogue: BN + SELU + NHWC store
    _Float16* db = dst + ((size_t)b << 22);
    #pragma unroll
    for (int m = 0; m < 2; ++m) {
        const int cob = (mh * 2 + m) * 16 + quad * 4;
        floatx4 sc = *(const floatx4*)(&s_sc[cob]);
        floatx4 bs = *(const floatx4*)(&s_bs[cob]);
        #pragma unroll
        for (int ni = 0; ni < 8; ++ni) {
            half4 ov;
            #pragma unroll
            for (int r = 0; r < 4; ++r)
                ov[r] = (_Float16)selu_f(acc[m][ni][r] * sc[r] + bs[r]);
            const int row = h0 + rh * 8 + ni, col = w0 + l15;
            *(half4*)(db + ((((row << 8) + col) << 6) + cob)) = ov;
        }
    }
}

// ------------- conv_out: 64 -> 3, BN, SELU, + interpolate_zeros(X), fp32 out -------------
__global__ __launch_bounds__(256) void k_conv_out_mfma(
    const _Float16* __restrict__ src, const _Float16* __restrict__ wb,
    const float* __restrict__ bconv, const float* __restrict__ g,
    const float* __restrict__ be, const float* __restrict__ bm,
    const float* __restrict__ bv, const float* __restrict__ X,
    float* __restrict__ out)
{
    __shared__ _Float16 s_in[324 * 72];
    const int tid = threadIdx.x;
    const int w0 = blockIdx.x * 16, h0 = blockIdx.y * 16, b = blockIdx.z;
    const _Float16* sb = src + ((size_t)b << 22);

    for (int idx = tid; idx < 2592; idx += 256) {
        int r = idx / 144, cpos = idx - r * 144;
        int col = cpos >> 3, sub = cpos & 7;
        int gh = h0 - 1 + r, gw = w0 - 1 + col;
        half8 val = {0, 0, 0, 0, 0, 0, 0, 0};
        if ((unsigned)gh < 256u && (unsigned)gw < 256u)
            val = *(const half8*)(sb + ((((gh << 8) + gw) << 6) + (sub << 3)));
        *(half8*)(&s_in[(r * 18 + col) * 72 + (sub << 3)]) = val;
    }
    __syncthreads();

    const int wv = tid >> 6, L = tid & 63, quad = L >> 4, l15 = L & 15;
    floatx4 acc[4];
    #pragma unroll
    for (int ni = 0; ni < 4; ++ni) acc[ni] = (floatx4){0.f, 0.f, 0.f, 0.f};

    #pragma unroll
    for (int t = 0; t < 18; ++t) {
        const int s = t >> 1, ci0 = (t & 1) << 5;
        const int kh = s / 3, kw = s - kh * 3;
        half8 a = *(const half8*)(wb + (t * 64 + L) * 8);
        #pragma unroll
        for (int ni = 0; ni < 4; ++ni) {
            const int row = wv * 4 + ni + kh, col = l15 + kw;
            half8 bfr = *(const half8*)(&s_in[(row * 18 + col) * 72 + ci0 + quad * 8]);
            acc[ni] = __builtin_amdgcn_mfma_f32_16x16x32_f16(a, bfr, acc[ni], 0, 0, 0);
        }
    }

    if (quad == 0) {
        float sc[3], bs[3];
        #pragma unroll
        for (int co = 0; co < 3; ++co) {
            sc[co] = g[co] * rsqrtf(bv[co] + EPS);
            bs[co] = (bconv[co] - bm[co]) * sc[co] + be[co];
        }
        #pragma unroll
        for (int ni = 0; ni < 4; ++ni) {
            const int h = h0 + wv * 4 + ni, wc = w0 + l15;
            #pragma unroll
            for (int co = 0; co < 3; ++co) {
                float val = selu_f(acc[ni][co] * sc[co] + bs[co]);
                const float* Xc = X + ((size_t)(b * 3 + co) << 16);
                float x = Xc[(h << 8) + wc];
                float res;
                if (x == 0.f) {
                    float lft = (wc > 0)   ? Xc[(h << 8) + wc - 1] : 0.f;
                    float rgt = (wc < 255) ? Xc[(h << 8) + wc + 1] : 0.f;
                    float top = (h > 0)    ? Xc[((h - 1) << 8) + wc] : 0.f;
                    float bot = (h < 255)  ? Xc[((h + 1) << 8) + wc] : 0.f;
                    float sm = lft + rgt + top + bot;
                    int cnt = (lft > 0.f) + (rgt > 0.f) + (top > 0.f) + (bot > 0.f);
                    res = cnt > 0 ? sm / (float)cnt : 0.f;
                } else {
                    res = x;
                }
                out[((b * 3 + co) << 16) + (h << 8) + wc] = val + res;
            }
        }
    }
}

extern "C" void kernel_launch(void* const* d_in, const int* in_sizes, int n_in,
                              void* d_out, int out_size, void* d_ws, size_t ws_size,
                              hipStream_t stream) {
    (void)in_sizes; (void)n_in; (void)out_size; (void)ws_size;
    const float* X    = (const float*)d_in[0];
    const float* w_in = (const float*)d_in[1];
    const float* b_in = (const float*)d_in[2];
    const float* g_in = (const float*)d_in[3];
    const float* be_in= (const float*)d_in[4];
    const float* m_in = (const float*)d_in[5];
    const float* v_in = (const float*)d_in[6];
    const float* w_h  = (const float*)d_in[7];
    const float* b_h  = (const float*)d_in[8];
    const float* g_h  = (const float*)d_in[9];
    const float* be_h = (const float*)d_in[10];
    const float* m_h  = (const float*)d_in[11];
    const float* v_h  = (const float*)d_in[12];
    const float* w_o  = (const float*)d_in[13];
    const float* b_o  = (const float*)d_in[14];
    const float* g_o  = (const float*)d_in[15];
    const float* be_o = (const float*)d_in[16];
    const float* m_o  = (const float*)d_in[17];
    const float* v_o  = (const float*)d_in[18];
    float* out = (float*)d_out;

    // ws layout (fp16 elems): act0[2^24] act1[2^24] wb_h[36864] wb_in[2048] wb_out[9216] zp[32]
    _Float16* act0  = (_Float16*)d_ws;
    _Float16* act1  = act0 + ((size_t)1 << 24);
    _Float16* wb_h  = act1 + ((size_t)1 << 24);
    _Float16* wb_in = wb_h + 36864;
    _Float16* wb_out= wb_in + 2048;
    _Float16* zp    = wb_out + 9216;

    dim3 grid(16, 16, 4), block(256);
    k_prep<<<188, 256, 0, stream>>>(w_h, w_in, w_o, wb_h, wb_in, wb_out, zp);
    k_conv_in_mfma<<<grid, block, 0, stream>>>(X, wb_in, b_in, g_in, be_in, m_in, v_in, act0);
    _Float16* src = act0;
    _Float16* dst = act1;
    for (int i = 0; i < 18; ++i) {
        k_hidden_v4<<<grid, block, 0, stream>>>(src, wb_h, b_h, g_h, be_h, m_h, v_h, zp, dst);
        _Float16* t = src; src = dst; dst = t;
    }
    k_conv_out_mfma<<<grid, block, 0, stream>>>(src, wb_out, b_o, g_o, be_o, m_o, v_o, X, out);
}

// Round 4
// 638.348 us; speedup vs baseline: 1.8415x; 1.8415x over previous
//
#include <hip/hip_runtime.h>

#define EPS 1e-5f
#define SELU_L 1.0507009873554805f
#define SELU_A 1.6732632423543772f
#define SELU_LA (SELU_L * SELU_A)

typedef _Float16 half8 __attribute__((ext_vector_type(8)));
typedef _Float16 half4 __attribute__((ext_vector_type(4)));
typedef float floatx4 __attribute__((ext_vector_type(4)));

__device__ __forceinline__ float selu_f(float x) {
    return x > 0.f ? SELU_L * x : SELU_LA * (__expf(x) - 1.f);
}

// async global->LDS, 16B per lane; LDS dest is wave-uniform base + lane*16
__device__ __forceinline__ void gload_lds16(const _Float16* g, _Float16* l) {
    __builtin_amdgcn_global_load_lds(
        (const __attribute__((address_space(1))) void*)g,
        (__attribute__((address_space(3))) void*)l, 16, 0, 0);
}

// ------------- weight swizzle prep: A-operand fragment order, fp16 -------------
// wb_h : [t=18][mi=4][L=64][j=8]  co = mi*16 + (L&15), ci = (t&1)*32 + (L>>4)*8 + j, s = t>>1
// wb_in: [mi=4][L=64][j=8]        k = (L>>4)*8+j -> s=k/3, ci=k%3 (k>=27 -> 0)
// wb_out:[t=18][L=64][j=8]        co = L&15 (valid <3), ci/s as wb_h
// zp   : 32 halves of zeros (OOB redirect target for global_load_lds staging)
__global__ __launch_bounds__(256) void k_prep(
    const float* __restrict__ w_h, const float* __restrict__ w_in,
    const float* __restrict__ w_out, _Float16* __restrict__ wb_h,
    _Float16* __restrict__ wb_in, _Float16* __restrict__ wb_out,
    _Float16* __restrict__ zp)
{
    int i = blockIdx.x * 256 + threadIdx.x;
    if (i < 32) zp[i] = (_Float16)0.f;  // zero page (ws is poisoned between runs)
    if (i < 36864) {
        int t = i >> 11;
        int rem = i & 2047;
        int mi = rem >> 9;
        int L = (rem >> 3) & 63;
        int j = i & 7;
        int co = mi * 16 + (L & 15);
        int ci = ((t & 1) << 5) + ((L >> 4) << 3) + j;
        int s = t >> 1;
        wb_h[i] = (_Float16)w_h[(co * 64 + ci) * 9 + s];
    } else if (i < 36864 + 2048) {
        int e = i - 36864;
        int mi = e >> 9;
        int L = (e >> 3) & 63;
        int j = e & 7;
        int co = mi * 16 + (L & 15);
        int k = ((L >> 4) << 3) + j;
        _Float16 val = (_Float16)0.f;
        if (k < 27) {
            int s = k / 3, ci = k - s * 3;
            val = (_Float16)w_in[(co * 3 + ci) * 9 + s];
        }
        wb_in[e] = val;
    } else if (i < 36864 + 2048 + 9216) {
        int e = i - 36864 - 2048;
        int t = e >> 9;
        int L = (e >> 3) & 63;
        int j = e & 7;
        int co = L & 15;
        int ci = ((t & 1) << 5) + ((L >> 4) << 3) + j;
        int s = t >> 1;
        _Float16 val = (_Float16)0.f;
        if (co < 3) val = (_Float16)w_out[(co * 64 + ci) * 9 + s];
        wb_out[e] = val;
    }
}

// ------------- conv_in: 3 -> 64, BN, SELU, NHWC fp16 out (MFMA, K=32) -------------
__global__ __launch_bounds__(256) void k_conv_in_mfma(
    const float* __restrict__ X, const _Float16* __restrict__ wb,
    const float* __restrict__ bconv, const float* __restrict__ g,
    const float* __restrict__ be, const float* __restrict__ bm,
    const float* __restrict__ bv, _Float16* __restrict__ dst)
{
    __shared__ float s_x[3][18][18];
    __shared__ float s_sc[64], s_bs[64];
    const int tid = threadIdx.x;
    const int w0 = blockIdx.x * 16, h0 = blockIdx.y * 16, b = blockIdx.z;

    if (tid < 64) {
        float sc = g[tid] * rsqrtf(bv[tid] + EPS);
        s_sc[tid] = sc;
        s_bs[tid] = (bconv[tid] - bm[tid]) * sc + be[tid];
    }
    for (int idx = tid; idx < 3 * 324; idx += 256) {
        int ci = idx / 324, rem = idx - ci * 324;
        int r = rem / 18, c = rem - r * 18;
        int gh = h0 - 1 + r, gw = w0 - 1 + c;
        float val = 0.f;
        if ((unsigned)gh < 256u && (unsigned)gw < 256u)
            val = X[((b * 3 + ci) << 16) + (gh << 8) + gw];
        s_x[ci][r][c] = val;
    }
    __syncthreads();

    const int wv = tid >> 6, L = tid & 63, quad = L >> 4, l15 = L & 15;
    half8 a[4];
    #pragma unroll
    for (int mi = 0; mi < 4; ++mi)
        a[mi] = *(const half8*)(wb + (mi * 64 + L) * 8);

    floatx4 acc[4][4];
    #pragma unroll
    for (int mi = 0; mi < 4; ++mi)
        #pragma unroll
        for (int ni = 0; ni < 4; ++ni) acc[mi][ni] = (floatx4){0.f, 0.f, 0.f, 0.f};

    #pragma unroll
    for (int ni = 0; ni < 4; ++ni) {
        half8 bfr;
        #pragma unroll
        for (int j = 0; j < 8; ++j) {
            int k = quad * 8 + j;
            float xv = 0.f;
            if (k < 27) {
                int s = k / 3, ci = k - s * 3;
                int kh = s / 3, kw = s - kh * 3;
                xv = s_x[ci][wv * 4 + ni + kh][l15 + kw];
            }
            bfr[j] = (_Float16)xv;
        }
        #pragma unroll
        for (int mi = 0; mi < 4; ++mi)
            acc[mi][ni] = __builtin_amdgcn_mfma_f32_16x16x32_f16(a[mi], bfr, acc[mi][ni], 0, 0, 0);
    }

    _Float16* db = dst + ((size_t)b << 22);  // b*256*256*64
    #pragma unroll
    for (int mi = 0; mi < 4; ++mi) {
        const int cob = mi * 16 + quad * 4;
        floatx4 sc = *(const floatx4*)(&s_sc[cob]);
        floatx4 bs = *(const floatx4*)(&s_bs[cob]);
        #pragma unroll
        for (int ni = 0; ni < 4; ++ni) {
            half4 ov;
            #pragma unroll
            for (int r = 0; r < 4; ++r)
                ov[r] = (_Float16)selu_f(acc[mi][ni][r] * sc[r] + bs[r]);
            const int row = h0 + wv * 4 + ni, col = w0 + l15;
            *(half4*)(db + ((((row << 8) + col) << 6) + cob)) = ov;
        }
    }
}

// ------------- hidden v5: weights in LDS (72 KB, staged once/block), 512 threads, ------
// ------------- persistent 4-tile blocks, double-buffered act tile, gload_lds ----------
// (rounds 1-3 post-mortem: register-resident weights (144-288 VGPR) always spill —
//  hipcc caps the budget at 128 regardless of launch_bounds/waves_per_eu. LDS is the
//  only storage the allocator can't spill. 72 KB weights + 2x41 KB act = 158 KB/CU.)
// Wave = (rq=row-quarter, mh=chan-half): 4 rows x 32 chans; acc = 32 VGPRs. 8 waves =
// 2 waves/SIMD. A-frags: contiguous 1KB/wave LDS reads (conflict-free). B-frags: XOR
// chunk swizzle, verified 0 conflicts in v2-v4.
__global__ __launch_bounds__(512, 2) void k_hidden_v5(
    const _Float16* __restrict__ src, const _Float16* __restrict__ wb,
    const float* __restrict__ bconv, const float* __restrict__ g,
    const float* __restrict__ be, const float* __restrict__ bm,
    const float* __restrict__ bv, const _Float16* __restrict__ zp,
    _Float16* __restrict__ dst)
{
    __shared__ _Float16 s_w[36864];        // 73728 B: full weight set
    __shared__ _Float16 s_act[2][20992];   // 2 x 41984 B (41 wave-chunks incl. pad)
    __shared__ float s_sc[64], s_bs[64];
    const int tid = threadIdx.x;
    const int wv = tid >> 6, L = tid & 63, quad = L >> 4, l15 = L & 15;
    const int rq = wv >> 1, mh = wv & 1;   // row-quarter, channel-half

    if (tid < 64) {
        float sc = g[tid] * rsqrtf(bv[tid] + EPS);
        s_sc[tid] = sc;
        s_bs[tid] = (bconv[tid] - bm[tid]) * sc + be[tid];
    }

    // ---- weights -> LDS once per block: 72 wave-chunks x 1 KB, linear = wb order ----
    #pragma unroll
    for (int k = 0; k < 9; ++k) {
        const int wc = k * 8 + wv;
        gload_lds16(wb + ((wc << 6) + L) * 8, &s_w[wc << 9]);
    }

    // ---- stage one 18x18x64 halo tile (2592 chunks = 40.5 -> 41 wave-chunks) ----
    auto stage = [&](int tau, int buf) {
        const int b = tau >> 8, rem = tau & 255;
        const int h0 = (rem >> 4) << 4, w0 = (rem & 15) << 4;
        const _Float16* sb = src + ((size_t)b << 22);
        #pragma unroll
        for (int k = 0; k < 6; ++k) {
            const int wc = k * 8 + wv;          // wave-uniform -> no divergence at wave level
            if (wc < 41) {
                const int p = (wc << 3) + (L >> 3);   // pixel (0..327; >=324 is pad)
                const int sd = (L & 7) ^ (p & 7);     // source chunk (pre-swizzle)
                const int rp = p / 18, cl = p - rp * 18;
                const int gh = h0 - 1 + rp, gw = w0 - 1 + cl;
                const _Float16* gp = (p < 324 && (unsigned)gh < 256u && (unsigned)gw < 256u)
                    ? sb + ((((gh << 8) + gw) << 6) + (sd << 3)) : zp;
                gload_lds16(gp, &s_act[buf][wc << 9]);
            }
        }
    };

    const int tau0 = blockIdx.x << 2;   // 4 consecutive tiles (shared halo -> L2 hits)
    stage(tau0, 0);
    __syncthreads();   // drains vmcnt: weights + tile0 staging complete

    for (int ti = 0; ti < 4; ++ti) {
        const int tau = tau0 + ti, cur = ti & 1;
        if (ti < 3) stage(tau + 1, cur ^ 1);   // issue-early: latency hides under MFMA

        floatx4 acc[2][4];
        #pragma unroll
        for (int m = 0; m < 2; ++m)
            #pragma unroll
            for (int ni = 0; ni < 4; ++ni) acc[m][ni] = (floatx4){0.f, 0.f, 0.f, 0.f};

        const _Float16* bufp = &s_act[cur][0];
        #pragma unroll
        for (int t = 0; t < 18; ++t) {
            const int s = t >> 1;
            const int kh = s / 3, kw = s - kh * 3;
            const int sb8 = ((t & 1) << 2) + quad;   // chunk slot within pixel
            half8 a0 = *(const half8*)(&s_w[((t * 4 + mh * 2 + 0) * 64 + L) * 8]);
            half8 a1 = *(const half8*)(&s_w[((t * 4 + mh * 2 + 1) * 64 + L) * 8]);
            #pragma unroll
            for (int ni = 0; ni < 4; ++ni) {
                const int p = (rq * 4 + ni + kh) * 18 + l15 + kw;
                half8 bfr = *(const half8*)(bufp + (p << 6) + (((p & 7) ^ sb8) << 3));
                acc[0][ni] = __builtin_amdgcn_mfma_f32_16x16x32_f16(a0, bfr, acc[0][ni], 0, 0, 0);
                acc[1][ni] = __builtin_amdgcn_mfma_f32_16x16x32_f16(a1, bfr, acc[1][ni], 0, 0, 0);
            }
        }

        // epilogue: BN + SELU + NHWC store
        const int b = tau >> 8, rem = tau & 255;
        const int h0 = (rem >> 4) << 4, w0 = (rem & 15) << 4;
        _Float16* db = dst + ((size_t)b << 22);
        #pragma unroll
        for (int m = 0; m < 2; ++m) {
            const int cob = (mh * 2 + m) * 16 + quad * 4;
            floatx4 sc = *(const floatx4*)(&s_sc[cob]);
            floatx4 bs = *(const floatx4*)(&s_bs[cob]);
            #pragma unroll
            for (int ni = 0; ni < 4; ++ni) {
                half4 ov;
                #pragma unroll
                for (int r = 0; r < 4; ++r)
                    ov[r] = (_Float16)selu_f(acc[m][ni][r] * sc[r] + bs[r]);
                const int row = h0 + rq * 4 + ni, col = w0 + l15;
                *(half4*)(db + ((((row << 8) + col) << 6) + cob)) = ov;
            }
        }
        __syncthreads();   // all waves done with buf[cur]; next iter may overwrite it
    }
}

// ------------- conv_out: 64 -> 3, BN, SELU, + interpolate_zeros(X), fp32 out -------------
__global__ __launch_bounds__(256) void k_conv_out_mfma(
    const _Float16* __restrict__ src, const _Float16* __restrict__ wb,
    const float* __restrict__ bconv, const float* __restrict__ g,
    const float* __restrict__ be, const float* __restrict__ bm,
    const float* __restrict__ bv, const float* __restrict__ X,
    float* __restrict__ out)
{
    __shared__ _Float16 s_in[324 * 72];
    const int tid = threadIdx.x;
    const int w0 = blockIdx.x * 16, h0 = blockIdx.y * 16, b = blockIdx.z;
    const _Float16* sb = src + ((size_t)b << 22);

    for (int idx = tid; idx < 2592; idx += 256) {
        int r = idx / 144, cpos = idx - r * 144;
        int col = cpos >> 3, sub = cpos & 7;
        int gh = h0 - 1 + r, gw = w0 - 1 + col;
        half8 val = {0, 0, 0, 0, 0, 0, 0, 0};
        if ((unsigned)gh < 256u && (unsigned)gw < 256u)
            val = *(const half8*)(sb + ((((gh << 8) + gw) << 6) + (sub << 3)));
        *(half8*)(&s_in[(r * 18 + col) * 72 + (sub << 3)]) = val;
    }
    __syncthreads();

    const int wv = tid >> 6, L = tid & 63, quad = L >> 4, l15 = L & 15;
    floatx4 acc[4];
    #pragma unroll
    for (int ni = 0; ni < 4; ++ni) acc[ni] = (floatx4){0.f, 0.f, 0.f, 0.f};

    #pragma unroll
    for (int t = 0; t < 18; ++t) {
        const int s = t >> 1, ci0 = (t & 1) << 5;
        const int kh = s / 3, kw = s - kh * 3;
        half8 a = *(const half8*)(wb + (t * 64 + L) * 8);
        #pragma unroll
        for (int ni = 0; ni < 4; ++ni) {
            const int row = wv * 4 + ni + kh, col = l15 + kw;
            half8 bfr = *(const half8*)(&s_in[(row * 18 + col) * 72 + ci0 + quad * 8]);
            acc[ni] = __builtin_amdgcn_mfma_f32_16x16x32_f16(a, bfr, acc[ni], 0, 0, 0);
        }
    }

    if (quad == 0) {
        float sc[3], bs[3];
        #pragma unroll
        for (int co = 0; co < 3; ++co) {
            sc[co] = g[co] * rsqrtf(bv[co] + EPS);
            bs[co] = (bconv[co] - bm[co]) * sc[co] + be[co];
        }
        #pragma unroll
        for (int ni = 0; ni < 4; ++ni) {
            const int h = h0 + wv * 4 + ni, wc = w0 + l15;
            #pragma unroll
            for (int co = 0; co < 3; ++co) {
                float val = selu_f(acc[ni][co] * sc[co] + bs[co]);
                const float* Xc = X + ((size_t)(b * 3 + co) << 16);
                float x = Xc[(h << 8) + wc];
                float res;
                if (x == 0.f) {
                    float lft = (wc > 0)   ? Xc[(h << 8) + wc - 1] : 0.f;
                    float rgt = (wc < 255) ? Xc[(h << 8) + wc + 1] : 0.f;
                    float top = (h > 0)    ? Xc[((h - 1) << 8) + wc] : 0.f;
                    float bot = (h < 255)  ? Xc[((h + 1) << 8) + wc] : 0.f;
                    float sm = lft + rgt + top + bot;
                    int cnt = (lft > 0.f) + (rgt > 0.f) + (top > 0.f) + (bot > 0.f);
                    res = cnt > 0 ? sm / (float)cnt : 0.f;
                } else {
                    res = x;
                }
                out[((b * 3 + co) << 16) + (h << 8) + wc] = val + res;
            }
        }
    }
}

extern "C" void kernel_launch(void* const* d_in, const int* in_sizes, int n_in,
                              void* d_out, int out_size, void* d_ws, size_t ws_size,
                              hipStream_t stream) {
    (void)in_sizes; (void)n_in; (void)out_size; (void)ws_size;
    const float* X    = (const float*)d_in[0];
    const float* w_in = (const float*)d_in[1];
    const float* b_in = (const float*)d_in[2];
    const float* g_in = (const float*)d_in[3];
    const float* be_in= (const float*)d_in[4];
    const float* m_in = (const float*)d_in[5];
    const float* v_in = (const float*)d_in[6];
    const float* w_h  = (const float*)d_in[7];
    const float* b_h  = (const float*)d_in[8];
    const float* g_h  = (const float*)d_in[9];
    const float* be_h = (const float*)d_in[10];
    const float* m_h  = (const float*)d_in[11];
    const float* v_h  = (const float*)d_in[12];
    const float* w_o  = (const float*)d_in[13];
    const float* b_o  = (const float*)d_in[14];
    const float* g_o  = (const float*)d_in[15];
    const float* be_o = (const float*)d_in[16];
    const float* m_o  = (const float*)d_in[17];
    const float* v_o  = (const float*)d_in[18];
    float* out = (float*)d_out;

    // ws layout (fp16 elems): act0[2^24] act1[2^24] wb_h[36864] wb_in[2048] wb_out[9216] zp[32]
    _Float16* act0  = (_Float16*)d_ws;
    _Float16* act1  = act0 + ((size_t)1 << 24);
    _Float16* wb_h  = act1 + ((size_t)1 << 24);
    _Float16* wb_in = wb_h + 36864;
    _Float16* wb_out= wb_in + 2048;
    _Float16* zp    = wb_out + 9216;

    dim3 grid(16, 16, 4), block(256);
    k_prep<<<188, 256, 0, stream>>>(w_h, w_in, w_o, wb_h, wb_in, wb_out, zp);
    k_conv_in_mfma<<<grid, block, 0, stream>>>(X, wb_in, b_in, g_in, be_in, m_in, v_in, act0);
    _Float16* src = act0;
    _Float16* dst = act1;
    for (int i = 0; i < 18; ++i) {
        k_hidden_v5<<<256, 512, 0, stream>>>(src, wb_h, b_h, g_h, be_h, m_h, v_h, zp, dst);
        _Float16* t = src; src = dst; dst = t;
    }
    k_conv_out_mfma<<<grid, block, 0, stream>>>(src, wb_out, b_o, g_o, be_o, m_o, v_o, X, out);
}

// Round 6
// 612.646 us; speedup vs baseline: 1.9187x; 1.0420x over previous
//
#include <hip/hip_runtime.h>

#define EPS 1e-5f
#define SELU_L 1.0507009873554805f
#define SELU_A 1.6732632423543772f
#define SELU_LA (SELU_L * SELU_A)

typedef _Float16 half8 __attribute__((ext_vector_type(8)));
typedef _Float16 half4 __attribute__((ext_vector_type(4)));
typedef float floatx4 __attribute__((ext_vector_type(4)));

__device__ __forceinline__ float selu_f(float x) {
    return x > 0.f ? SELU_L * x : SELU_LA * (__expf(x) - 1.f);
}

// async global->LDS, 16B per lane; LDS dest is wave-uniform base + lane*16
__device__ __forceinline__ void gload_lds16(const _Float16* g, _Float16* l) {
    __builtin_amdgcn_global_load_lds(
        (const __attribute__((address_space(1))) void*)g,
        (__attribute__((address_space(3))) void*)l, 16, 0, 0);
}

// ------------- weight swizzle prep: A-operand fragment order, fp16 -------------
// wb_h : [t=18][mi=4][L=64][j=8]  co = mi*16 + (L&15), ci = (t&1)*32 + (L>>4)*8 + j, s = t>>1
// wb_in: [mi=4][L=64][j=8]        k = (L>>4)*8+j -> s=k/3, ci=k%3 (k>=27 -> 0)
// wb_out:[t=18][L=64][j=8]        co = L&15 (valid <3), ci/s as wb_h
// zp   : 32 halves of zeros (OOB redirect target for global_load_lds staging)
__global__ __launch_bounds__(256) void k_prep(
    const float* __restrict__ w_h, const float* __restrict__ w_in,
    const float* __restrict__ w_out, _Float16* __restrict__ wb_h,
    _Float16* __restrict__ wb_in, _Float16* __restrict__ wb_out,
    _Float16* __restrict__ zp)
{
    int i = blockIdx.x * 256 + threadIdx.x;
    if (i < 32) zp[i] = (_Float16)0.f;  // zero page (ws is poisoned between runs)
    if (i < 36864) {
        int t = i >> 11;
        int rem = i & 2047;
        int mi = rem >> 9;
        int L = (rem >> 3) & 63;
        int j = i & 7;
        int co = mi * 16 + (L & 15);
        int ci = ((t & 1) << 5) + ((L >> 4) << 3) + j;
        int s = t >> 1;
        wb_h[i] = (_Float16)w_h[(co * 64 + ci) * 9 + s];
    } else if (i < 36864 + 2048) {
        int e = i - 36864;
        int mi = e >> 9;
        int L = (e >> 3) & 63;
        int j = e & 7;
        int co = mi * 16 + (L & 15);
        int k = ((L >> 4) << 3) + j;
        _Float16 val = (_Float16)0.f;
        if (k < 27) {
            int s = k / 3, ci = k - s * 3;
            val = (_Float16)w_in[(co * 3 + ci) * 9 + s];
        }
        wb_in[e] = val;
    } else if (i < 36864 + 2048 + 9216) {
        int e = i - 36864 - 2048;
        int t = e >> 9;
        int L = (e >> 3) & 63;
        int j = e & 7;
        int co = L & 15;
        int ci = ((t & 1) << 5) + ((L >> 4) << 3) + j;
        int s = t >> 1;
        _Float16 val = (_Float16)0.f;
        if (co < 3) val = (_Float16)w_out[(co * 64 + ci) * 9 + s];
        wb_out[e] = val;
    }
}

// ------------- conv_in: 3 -> 64, BN, SELU, NHWC fp16 out (MFMA, K=32) -------------
__global__ __launch_bounds__(256) void k_conv_in_mfma(
    const float* __restrict__ X, const _Float16* __restrict__ wb,
    const float* __restrict__ bconv, const float* __restrict__ g,
    const float* __restrict__ be, const float* __restrict__ bm,
    const float* __restrict__ bv, _Float16* __restrict__ dst)
{
    __shared__ float s_x[3][18][18];
    __shared__ float s_sc[64], s_bs[64];
    const int tid = threadIdx.x;
    const int w0 = blockIdx.x * 16, h0 = blockIdx.y * 16, b = blockIdx.z;

    if (tid < 64) {
        float sc = g[tid] * rsqrtf(bv[tid] + EPS);
        s_sc[tid] = sc;
        s_bs[tid] = (bconv[tid] - bm[tid]) * sc + be[tid];
    }
    for (int idx = tid; idx < 3 * 324; idx += 256) {
        int ci = idx / 324, rem = idx - ci * 324;
        int r = rem / 18, c = rem - r * 18;
        int gh = h0 - 1 + r, gw = w0 - 1 + c;
        float val = 0.f;
        if ((unsigned)gh < 256u && (unsigned)gw < 256u)
            val = X[((b * 3 + ci) << 16) + (gh << 8) + gw];
        s_x[ci][r][c] = val;
    }
    __syncthreads();

    const int wv = tid >> 6, L = tid & 63, quad = L >> 4, l15 = L & 15;
    half8 a[4];
    #pragma unroll
    for (int mi = 0; mi < 4; ++mi)
        a[mi] = *(const half8*)(wb + (mi * 64 + L) * 8);

    floatx4 acc[4][4];
    #pragma unroll
    for (int mi = 0; mi < 4; ++mi)
        #pragma unroll
        for (int ni = 0; ni < 4; ++ni) acc[mi][ni] = (floatx4){0.f, 0.f, 0.f, 0.f};

    #pragma unroll
    for (int ni = 0; ni < 4; ++ni) {
        half8 bfr;
        #pragma unroll
        for (int j = 0; j < 8; ++j) {
            int k = quad * 8 + j;
            float xv = 0.f;
            if (k < 27) {
                int s = k / 3, ci = k - s * 3;
                int kh = s / 3, kw = s - kh * 3;
                xv = s_x[ci][wv * 4 + ni + kh][l15 + kw];
            }
            bfr[j] = (_Float16)xv;
        }
        #pragma unroll
        for (int mi = 0; mi < 4; ++mi)
            acc[mi][ni] = __builtin_amdgcn_mfma_f32_16x16x32_f16(a[mi], bfr, acc[mi][ni], 0, 0, 0);
    }

    _Float16* db = dst + ((size_t)b << 22);  // b*256*256*64
    #pragma unroll
    for (int mi = 0; mi < 4; ++mi) {
        const int cob = mi * 16 + quad * 4;
        floatx4 sc = *(const floatx4*)(&s_sc[cob]);
        floatx4 bs = *(const floatx4*)(&s_bs[cob]);
        #pragma unroll
        for (int ni = 0; ni < 4; ++ni) {
            half4 ov;
            #pragma unroll
            for (int r = 0; r < 4; ++r)
                ov[r] = (_Float16)selu_f(acc[mi][ni][r] * sc[r] + bs[r]);
            const int row = h0 + wv * 4 + ni, col = w0 + l15;
            *(half4*)(db + ((((row << 8) + col) << 6) + cob)) = ov;
        }
    }
}

// ------------- hidden v6: v5 + tap-reuse inner loop (1 B-read feeds up to 6 MFMAs) ----
// (round 4 post-mortem: v5 at ~32 us/layer vs 11.5 us LDS-BW floor -> exposed ds_read
//  latency with only 2 waves/SIMD and a {read -> 2 MFMA} inner body. Restructure as
//  (h, kw, j): hoist 6 A-frags per (h,kw) into regs, then each B-frag read at row
//  rq*4+j feeds all valid kh taps x 2 m. Reads/wave/tile 108 -> 72; LDS traffic
//  864 -> 576 KB/tile; regs ~90 < 128 budget, no spill. K-sum order permuted (fp32
//  reorder noise ~1e-5, negligible). Address set identical to verified-0-conflict v5.)
// (round 5: resubmit verbatim — bench failed on container acquisition, not the kernel.)
__global__ __launch_bounds__(512, 2) void k_hidden_v6(
    const _Float16* __restrict__ src, const _Float16* __restrict__ wb,
    const float* __restrict__ bconv, const float* __restrict__ g,
    const float* __restrict__ be, const float* __restrict__ bm,
    const float* __restrict__ bv, const _Float16* __restrict__ zp,
    _Float16* __restrict__ dst)
{
    __shared__ _Float16 s_w[36864];        // 73728 B: full weight set
    __shared__ _Float16 s_act[2][20992];   // 2 x 41984 B (41 wave-chunks incl. pad)
    __shared__ float s_sc[64], s_bs[64];
    const int tid = threadIdx.x;
    const int wv = tid >> 6, L = tid & 63, quad = L >> 4, l15 = L & 15;
    const int rq = wv >> 1, mh = wv & 1;   // row-quarter, channel-half

    if (tid < 64) {
        float sc = g[tid] * rsqrtf(bv[tid] + EPS);
        s_sc[tid] = sc;
        s_bs[tid] = (bconv[tid] - bm[tid]) * sc + be[tid];
    }

    // ---- weights -> LDS once per block: 72 wave-chunks x 1 KB, linear = wb order ----
    #pragma unroll
    for (int k = 0; k < 9; ++k) {
        const int wc = k * 8 + wv;
        gload_lds16(wb + ((wc << 6) + L) * 8, &s_w[wc << 9]);
    }

    // ---- stage one 18x18x64 halo tile (2592 chunks = 40.5 -> 41 wave-chunks) ----
    auto stage = [&](int tau, int buf) {
        const int b = tau >> 8, rem = tau & 255;
        const int h0 = (rem >> 4) << 4, w0 = (rem & 15) << 4;
        const _Float16* sb = src + ((size_t)b << 22);
        #pragma unroll
        for (int k = 0; k < 6; ++k) {
            const int wc = k * 8 + wv;          // wave-uniform -> no divergence at wave level
            if (wc < 41) {
                const int p = (wc << 3) + (L >> 3);   // pixel (0..327; >=324 is pad)
                const int sd = (L & 7) ^ (p & 7);     // source chunk (pre-swizzle)
                const int rp = p / 18, cl = p - rp * 18;
                const int gh = h0 - 1 + rp, gw = w0 - 1 + cl;
                const _Float16* gp = (p < 324 && (unsigned)gh < 256u && (unsigned)gw < 256u)
                    ? sb + ((((gh << 8) + gw) << 6) + (sd << 3)) : zp;
                gload_lds16(gp, &s_act[buf][wc << 9]);
            }
        }
    };

    const int tau0 = blockIdx.x << 2;   // 4 consecutive tiles (shared halo -> L2 hits)
    stage(tau0, 0);
    __syncthreads();   // drains vmcnt: weights + tile0 staging complete

    for (int ti = 0; ti < 4; ++ti) {
        const int tau = tau0 + ti, cur = ti & 1;
        if (ti < 3) stage(tau + 1, cur ^ 1);   // issue-early: latency hides under MFMA

        floatx4 acc[2][4];
        #pragma unroll
        for (int m = 0; m < 2; ++m)
            #pragma unroll
            for (int ni = 0; ni < 4; ++ni) acc[m][ni] = (floatx4){0.f, 0.f, 0.f, 0.f};

        const _Float16* bufp = &s_act[cur][0];
        #pragma unroll
        for (int h = 0; h < 2; ++h) {          // k-half (ci 0-31 / 32-63)
            const int sb8 = (h << 2) + quad;   // chunk slot within pixel
            #pragma unroll
            for (int kw = 0; kw < 3; ++kw) {
                // A-cache: 6 frags (3 kh x 2 m) for this (h, kw)
                half8 ac[3][2];
                #pragma unroll
                for (int kh = 0; kh < 3; ++kh) {
                    const int t = ((kh * 3 + kw) << 1) + h;
                    ac[kh][0] = *(const half8*)(&s_w[((t * 4 + mh * 2 + 0) * 64 + L) * 8]);
                    ac[kh][1] = *(const half8*)(&s_w[((t * 4 + mh * 2 + 1) * 64 + L) * 8]);
                }
                #pragma unroll
                for (int j = 0; j < 6; ++j) {  // halo row offset; one B-read, <=6 MFMAs
                    const int p = (rq * 4 + j) * 18 + l15 + kw;
                    half8 bfr = *(const half8*)(bufp + (p << 6) + (((p & 7) ^ sb8) << 3));
                    #pragma unroll
                    for (int kh = 0; kh < 3; ++kh) {
                        const int ni = j - kh;
                        if (ni >= 0 && ni < 4) {
                            acc[0][ni] = __builtin_amdgcn_mfma_f32_16x16x32_f16(ac[kh][0], bfr, acc[0][ni], 0, 0, 0);
                            acc[1][ni] = __builtin_amdgcn_mfma_f32_16x16x32_f16(ac[kh][1], bfr, acc[1][ni], 0, 0, 0);
                        }
                    }
                }
            }
        }

        // epilogue: BN + SELU + NHWC store
        const int b = tau >> 8, rem = tau & 255;
        const int h0 = (rem >> 4) << 4, w0 = (rem & 15) << 4;
        _Float16* db = dst + ((size_t)b << 22);
        #pragma unroll
        for (int m = 0; m < 2; ++m) {
            const int cob = (mh * 2 + m) * 16 + quad * 4;
            floatx4 sc = *(const floatx4*)(&s_sc[cob]);
            floatx4 bs = *(const floatx4*)(&s_bs[cob]);
            #pragma unroll
            for (int ni = 0; ni < 4; ++ni) {
                half4 ov;
                #pragma unroll
                for (int r = 0; r < 4; ++r)
                    ov[r] = (_Float16)selu_f(acc[m][ni][r] * sc[r] + bs[r]);
                const int row = h0 + rq * 4 + ni, col = w0 + l15;
                *(half4*)(db + ((((row << 8) + col) << 6) + cob)) = ov;
            }
        }
        __syncthreads();   // all waves done with buf[cur]; next iter may overwrite it
    }
}

// ------------- conv_out: 64 -> 3, BN, SELU, + interpolate_zeros(X), fp32 out -------------
__global__ __launch_bounds__(256) void k_conv_out_mfma(
    const _Float16* __restrict__ src, const _Float16* __restrict__ wb,
    const float* __restrict__ bconv, const float* __restrict__ g,
    const float* __restrict__ be, const float* __restrict__ bm,
    const float* __restrict__ bv, const float* __restrict__ X,
    float* __restrict__ out)
{
    __shared__ _Float16 s_in[324 * 72];
    const int tid = threadIdx.x;
    const int w0 = blockIdx.x * 16, h0 = blockIdx.y * 16, b = blockIdx.z;
    const _Float16* sb = src + ((size_t)b << 22);

    for (int idx = tid; idx < 2592; idx += 256) {
        int r = idx / 144, cpos = idx - r * 144;
        int col = cpos >> 3, sub = cpos & 7;
        int gh = h0 - 1 + r, gw = w0 - 1 + col;
        half8 val = {0, 0, 0, 0, 0, 0, 0, 0};
        if ((unsigned)gh < 256u && (unsigned)gw < 256u)
            val = *(const half8*)(sb + ((((gh << 8) + gw) << 6) + (sub << 3)));
        *(half8*)(&s_in[(r * 18 + col) * 72 + (sub << 3)]) = val;
    }
    __syncthreads();

    const int wv = tid >> 6, L = tid & 63, quad = L >> 4, l15 = L & 15;
    floatx4 acc[4];
    #pragma unroll
    for (int ni = 0; ni < 4; ++ni) acc[ni] = (floatx4){0.f, 0.f, 0.f, 0.f};

    #pragma unroll
    for (int t = 0; t < 18; ++t) {
        const int s = t >> 1, ci0 = (t & 1) << 5;
        const int kh = s / 3, kw = s - kh * 3;
        half8 a = *(const half8*)(wb + (t * 64 + L) * 8);
        #pragma unroll
        for (int ni = 0; ni < 4; ++ni) {
            const int row = wv * 4 + ni + kh, col = l15 + kw;
            half8 bfr = *(const half8*)(&s_in[(row * 18 + col) * 72 + ci0 + quad * 8]);
            acc[ni] = __builtin_amdgcn_mfma_f32_16x16x32_f16(a, bfr, acc[ni], 0, 0, 0);
        }
    }

    if (quad == 0) {
        float sc[3], bs[3];
        #pragma unroll
        for (int co = 0; co < 3; ++co) {
            sc[co] = g[co] * rsqrtf(bv[co] + EPS);
            bs[co] = (bconv[co] - bm[co]) * sc[co] + be[co];
        }
        #pragma unroll
        for (int ni = 0; ni < 4; ++ni) {
            const int h = h0 + wv * 4 + ni, wc = w0 + l15;
            #pragma unroll
            for (int co = 0; co < 3; ++co) {
                float val = selu_f(acc[ni][co] * sc[co] + bs[co]);
                const float* Xc = X + ((size_t)(b * 3 + co) << 16);
                float x = Xc[(h << 8) + wc];
                float res;
                if (x == 0.f) {
                    float lft = (wc > 0)   ? Xc[(h << 8) + wc - 1] : 0.f;
                    float rgt = (wc < 255) ? Xc[(h << 8) + wc + 1] : 0.f;
                    float top = (h > 0)    ? Xc[((h - 1) << 8) + wc] : 0.f;
                    float bot = (h < 255)  ? Xc[((h + 1) << 8) + wc] : 0.f;
                    float sm = lft + rgt + top + bot;
                    int cnt = (lft > 0.f) + (rgt > 0.f) + (top > 0.f) + (bot > 0.f);
                    res = cnt > 0 ? sm / (float)cnt : 0.f;
                } else {
                    res = x;
                }
                out[((b * 3 + co) << 16) + (h << 8) + wc] = val + res;
            }
        }
    }
}

extern "C" void kernel_launch(void* const* d_in, const int* in_sizes, int n_in,
                              void* d_out, int out_size, void* d_ws, size_t ws_size,
                              hipStream_t stream) {
    (void)in_sizes; (void)n_in; (void)out_size; (void)ws_size;
    const float* X    = (const float*)d_in[0];
    const float* w_in = (const float*)d_in[1];
    const float* b_in = (const float*)d_in[2];
    const float* g_in = (const float*)d_in[3];
    const float* be_in= (const float*)d_in[4];
    const float* m_in = (const float*)d_in[5];
    const float* v_in = (const float*)d_in[6];
    const float* w_h  = (const float*)d_in[7];
    const float* b_h  = (const float*)d_in[8];
    const float* g_h  = (const float*)d_in[9];
    const float* be_h = (const float*)d_in[10];
    const float* m_h  = (const float*)d_in[11];
    const float* v_h  = (const float*)d_in[12];
    const float* w_o  = (const float*)d_in[13];
    const float* b_o  = (const float*)d_in[14];
    const float* g_o  = (const float*)d_in[15];
    const float* be_o = (const float*)d_in[16];
    const float* m_o  = (const float*)d_in[17];
    const float* v_o  = (const float*)d_in[18];
    float* out = (float*)d_out;

    // ws layout (fp16 elems): act0[2^24] act1[2^24] wb_h[36864] wb_in[2048] wb_out[9216] zp[32]
    _Float16* act0  = (_Float16*)d_ws;
    _Float16* act1  = act0 + ((size_t)1 << 24);
    _Float16* wb_h  = act1 + ((size_t)1 << 24);
    _Float16* wb_in = wb_h + 36864;
    _Float16* wb_out= wb_in + 2048;
    _Float16* zp    = wb_out + 9216;

    dim3 grid(16, 16, 4), block(256);
    k_prep<<<188, 256, 0, stream>>>(w_h, w_in, w_o, wb_h, wb_in, wb_out, zp);
    k_conv_in_mfma<<<grid, block, 0, stream>>>(X, wb_in, b_in, g_in, be_in, m_in, v_in, act0);
    _Float16* src = act0;
    _Float16* dst = act1;
    for (int i = 0; i < 18; ++i) {
        k_hidden_v6<<<256, 512, 0, stream>>>(src, wb_h, b_h, g_h, be_h, m_h, v_h, zp, dst);
        _Float16* t = src; src = dst; dst = t;
    }
    k_conv_out_mfma<<<grid, block, 0, stream>>>(src, wb_out, b_o, g_o, be_o, m_o, v_o, X, out);
}